// Round 9
// baseline (267.850 us; speedup 1.0000x reference)
//
#include <hip/hip_runtime.h>
#include <hip/hip_bf16.h>
#include <stdint.h>

// Problem constants
#define LNUM   2
#define F0     64
#define F1     32
#define NBASIS 8
#define WH     64     // radial MLP hidden width
#define RWN    192    // 2*F0 + 2*F1
#define NINVD  64
#define NVECD  16
#define BB     4
#define NN     512

// Tuning constants
#define TROWS  2048        // table rows over d in [0,8); rw(d>6) ~ 0 (no bias)
#define TSCALE 256.0f      // rows per unit d
#define NF     416         // per-node row: 8 slices x 48 [hm8|p0 8|p1 8|p2 8|hsv4|ga12] | xs3 | pad
#define SSPLIT 32          // sender splits
#define CHUNK  16          // NN / SSPLIT senders per block
#define ACC    160         // 64 (a0) + 96 (a1) accumulated features
#define RTILES 8           // receiver tiles of 64 per batch
#define TBLK   16          // table rows per block
#define INV_OFF (BB * NN * NVECD * 3)   // vecf comes first in d_out

typedef float f32x4 __attribute__((ext_vector_type(4)));
typedef uint32_t u32x16 __attribute__((ext_vector_type(16)));
typedef uint32_t u32x4v __attribute__((ext_vector_type(4)));

#define LOF(u) __uint_as_float((u) << 16)
#define HIF(u) __uint_as_float((u) & 0xffff0000u)
#define SF(vec, k) __uint_as_float((uint32_t)(vec)[k])

// Wave-uniform scalar loads (SMEM pipe). Readiness is guaranteed by the
// mandatory lgkmcnt(0) drain at the next __syncthreads (plus explicit
// waitcnt+sched_barrier at the consume site, per guide rule #18).
__device__ __forceinline__ u32x16 sload16(const float* base, uint32_t boff) {
  u32x16 r;
  asm volatile("s_load_dwordx16 %0, %1, %2" : "=s"(r) : "s"(base), "s"(boff));
  return r;
}
__device__ __forceinline__ u32x4v sload4(const float* base, uint32_t boff) {
  u32x4v r;
  asm volatile("s_load_dwordx4 %0, %1, %2" : "=s"(r) : "s"(base), "s"(boff));
  return r;
}

// ---------------------------------------------------------------------------
// Radial table: rw(d) = silu(rb(d) @ Wr1) @ Wr2, stored bf16, columns permuted
// into 8 slices of 24 = [w0(8)|w3(8)|w1(4)|w2(4)]; row stride 384 B.
// Row TROWS is all zeros (masked diagonal).
// TBLK=16 rows per block so Wr2 reads amortize 16x (192 threads, 1 col each).
// ---------------------------------------------------------------------------
__global__ void table_k(const float* __restrict__ Wr1, const float* __restrict__ Wr2,
                        __hip_bfloat16* __restrict__ table) {
  int blk = blockIdx.x;                  // 0 .. LNUM*130-1
  int l   = blk / 130;
  int bj  = blk - l * 130;
  int j0  = bj * TBLK;
  int t   = threadIdx.x;                 // 0..191
  __shared__ float hsh[TBLK][WH];
  // phase 1: hidden activations for TBLK rows (rows >= TROWS get h = 0)
  for (int idx = t; idx < TBLK * WH; idx += 192) {
    int rr = idx >> 6, hid = idx & 63;
    int j = j0 + rr;
    float val = 0.0f;
    if (j < TROWS) {
      float d = (float)j * (1.0f / TSCALE);
      float acc = 0.0f;
#pragma unroll
      for (int b = 0; b < NBASIS; b++) {
        float dd = d - (4.0f / 7.0f) * (float)b;   // centers = linspace(0,4,8)
        acc += __expf(-4.0f * dd * dd) * Wr1[(l * NBASIS + b) * WH + hid];
      }
      val = acc / (1.0f + __expf(-acc));           // silu
    }
    hsh[rr][hid] = val;
  }
  __syncthreads();
  // phase 2: one permuted output column per thread, all TBLK rows
  int w = t / 24, o = t - w * 24;
  int col;
  if      (o < 8)  col = 8 * w + o;              // w0 slice (cols 0..63)
  else if (o < 16) col = 64 + 8 * w + (o - 8);   // w3 slice (64..127)
  else if (o < 20) col = 128 + 4 * w + (o - 16); // w1 slice (128..159)
  else             col = 160 + 4 * w + (o - 20); // w2 slice (160..191)
  float acc[TBLK];
#pragma unroll
  for (int rr = 0; rr < TBLK; rr++) acc[rr] = 0.0f;
  for (int k = 0; k < WH; k++) {
    float wgt = Wr2[(l * WH + k) * RWN + col];
#pragma unroll
    for (int rr = 0; rr < TBLK; rr++) acc[rr] += hsh[rr][k] * wgt;
  }
#pragma unroll
  for (int rr = 0; rr < TBLK; rr++) {
    int j = j0 + rr;
    if (j <= TROWS)
      table[(size_t)(l * (TROWS + 1) + j) * RWN + t] = __float2bfloat16(acc[rr]);
  }
}

// h_s = broadcast embed row; h_v = 0
__global__ void init_k(const float* __restrict__ embed,
                       float* __restrict__ h_s, float* __restrict__ h_v) {
  int i = blockIdx.x * 256 + threadIdx.x;
  if (i < BB * NN * F0) h_s[i] = embed[i % F0];
  if (i < BB * NN * F1 * 3) h_v[i] = 0.0f;
}

// ---------------------------------------------------------------------------
// Per-node precompute, slice-major layout (weights pre-offset by caller):
// nf[node] = 8 slices of 48 floats: [hm(8)|p0(8)|p1(8)|p2(8)|hsv(4)|ga(12)]
//            then xs at 384..386; row stride 416 floats (1664 B, 64B-aligned).
// 256 threads = 4 waves x 2 node-iters = 8 nodes/block (weight reuse 8x).
// Each wave uses only its own [wid] LDS slot (no cross-wave sharing).
// ---------------------------------------------------------------------------
__global__ void nodeprep_k(const float* __restrict__ h_s, const float* __restrict__ h_v,
                           const float* __restrict__ x,
                           const float* __restrict__ Wm, const float* __restrict__ Wsv,
                           const float* __restrict__ Wvv, const float* __restrict__ Wv0,
                           float* __restrict__ nf) {
  int blk  = blockIdx.x;      // 0 .. BB*NN/8-1
  int tid  = threadIdx.x;     // 256
  int wid  = tid >> 6;
  int lane = tid & 63;
  __shared__ float hs[4][F0];
  __shared__ float hv[4][F1 * 3];
  for (int it = 0; it < 2; it++) {
    int node = blk * 8 + it * 4 + wid;
    hs[wid][lane] = h_s[(size_t)node * F0 + lane];
    hv[wid][lane] = h_v[(size_t)node * F1 * 3 + lane];
    if (lane < 32) hv[wid][64 + lane] = h_v[(size_t)node * F1 * 3 + 64 + lane];
    __syncthreads();
    float* out = nf + (size_t)node * NF;
    {  // hm[f] -> slice f>>3, pos f&7
      float a = 0.0f;
      for (int k = 0; k < F0; k++) a += hs[wid][k] * Wm[k * F0 + lane];
      out[(lane >> 3) * 48 + (lane & 7)] = a;
    }
    if (lane < F1) {  // hsv[c] -> slice c>>2, pos 32 + (c&3)
      float a = 0.0f;
      for (int k = 0; k < F0; k++) a += hs[wid][k] * Wsv[k * F1 + lane];
      out[(lane >> 2) * 48 + 32 + (lane & 3)] = a;
    }
    for (int o = lane; o < 96; o += 64) {  // ga: hvv[ch][i] -> slice ch>>2, 36+(ch&3)*3+i
      int ch = o / 3, i = o - ch * 3;
      float a = 0.0f;
      for (int f = 0; f < F1; f++) a += hv[wid][f * 3 + i] * Wvv[f * F1 + ch];
      out[(ch >> 2) * 48 + 36 + (ch & 3) * 3 + i] = a;
    }
    for (int o = lane; o < 192; o += 64) {  // p_i: hv0[i][f] -> slice f>>3, 8+8i+(f&7)
      int i = o >> 6, f = o & 63;
      float a = 0.0f;
      for (int c = 0; c < F1; c++) a += hv[wid][c * 3 + i] * Wv0[c * F0 + f];
      out[(f >> 3) * 48 + 8 + 8 * i + (f & 7)] = a;
    }
    if (lane < 3) out[384 + lane] = x[(size_t)node * 3 + lane];
    __syncthreads();
  }
}

// ---------------------------------------------------------------------------
// Message + scatter — EXACT R7 structure (proven): cooperative radial-row
// staging, single stage buffer, two barriers per sender-iteration; sender
// features via s_load into SGPRs.
// ---------------------------------------------------------------------------
#define LOADNEXT(ii)                                                      \
  {                                                                       \
    int ja0 = jt[ii][e0], ja1 = jt[ii][e1], ja2 = jt[ii][e2];             \
    c0 = *(const uint4*)(tb + (size_t)ja0 * 384 + bo0);                   \
    c1 = *(const uint4*)(tb + (size_t)ja1 * 384 + bo1);                   \
    c2 = *(const uint4*)(tb + (size_t)ja2 * 384 + bo2);                   \
  }

__launch_bounds__(512, 6)
__global__ void msg_k(const float* __restrict__ nf, const __hip_bfloat16* __restrict__ table_l,
                      const float* __restrict__ x, float* __restrict__ partial) {
  __shared__ uint32_t stage[6400];       // 25,600 B = 64 rows x 400 B
  __shared__ uint16_t jt[CHUNK][64];     //  2,048 B
  int bid = blockIdx.x;
  int b   = bid >> 8;                    // /(RTILES*SSPLIT)
  int rem = bid & 255;
  int rt  = rem >> 5;                    // receiver tile
  int ss  = rem & 31;                    // sender chunk
  int tid  = threadIdx.x;
  int w    = tid >> 6;                   // feature slice 0..7
  int lane = tid & 63;                   // local receiver
  int r    = rt * 64 + lane;
  int wu   = __builtin_amdgcn_readfirstlane(w);

  // precompute (sender, receiver) table-row indices for this block
#pragma unroll
  for (int m = 0; m < 2; m++) {
    int idx = tid + 512 * m;             // 1024 = CHUNK*64 entries
    int si = idx >> 6, e = idx & 63;
    int s = ss * CHUNK + si, rr = rt * 64 + e;
    const float* ps = x + ((size_t)b * NN + s) * 3;
    const float* pr = x + ((size_t)b * NN + rr) * 3;
    float v0 = pr[0] - ps[0], v1 = pr[1] - ps[1], v2 = pr[2] - ps[2];
    float d = sqrtf(v0 * v0 + v1 * v1 + v2 * v2);
    int j = (int)fminf(d * TSCALE + 0.5f, (float)(TROWS - 1));
    if (s == rr) j = TROWS;              // diagonal -> zero row
    jt[si][e] = (uint16_t)j;
  }

  const float* xp = x + ((size_t)b * NN + r) * 3;
  float xr0 = xp[0], xr1 = xp[1], xr2 = xp[2];

  // staging chunk map: q = tid + 512k -> row e = q/24, part p = q%24
  int q0 = tid, q1 = tid + 512, q2 = tid + 1024;
  int e0 = q0 / 24, p0 = q0 - 24 * e0;
  int e1 = q1 / 24, p1 = q1 - 24 * e1;
  int e2 = q2 / 24, p2 = q2 - 24 * e2;
  int wi0 = 25 * e0 + p0, wi1 = 25 * e1 + p1, wi2 = 25 * e2 + p2;
  int bo0 = p0 * 16, bo1 = p1 * 16, bo2 = p2 * 16;
  const char* tb = (const char*)table_l;

  float a0[8];
  float a1[12];
#pragma unroll
  for (int k = 0; k < 8; k++) a0[k] = 0.0f;
#pragma unroll
  for (int k = 0; k < 12; k++) a1[k] = 0.0f;

  __syncthreads();                       // jt ready

  uint4 c0, c1, c2;
  LOADNEXT(0);

  // SGPR feature prologue for sender 0
  uint32_t nrow0 = (uint32_t)(b * NN + ss * CHUNK) * (NF * 4);
  uint32_t nb0   = nrow0 + (uint32_t)wu * 192;
  u32x16 rB  = sload16(nf, nb0 + 128);   // hsv|ga
  u32x4v rX  = sload4 (nf, nrow0 + 1536);// xs
  u32x16 rA0 = sload16(nf, nb0);         // hm|p0
  u32x16 rA1 = sload16(nf, nb0 + 64);    // p1|p2

  int rb = 25 * lane + 3 * w;            // this thread's stage slice base

  for (int i = 0; i < CHUNK; i++) {
    __syncthreads();                     // stage free (prev compute done)
    ((uint4*)stage)[wi0] = c0;           // vmcnt auto-wait before ds_write
    ((uint4*)stage)[wi1] = c1;
    ((uint4*)stage)[wi2] = c2;
    __syncthreads();                     // stage ready (drains lgkm: s_loads done)
    if (i + 1 < CHUNK) LOADNEXT(i + 1);  // next rows fetched during compute
    asm volatile("s_waitcnt lgkmcnt(0)" ::: "memory");
    __builtin_amdgcn_sched_barrier(0);

    // geometry (xs in SGPRs)
    float v0 = xr0 - SF(rX, 0), v1 = xr1 - SF(rX, 1), v2 = xr2 - SF(rX, 2);
    float d2 = v0 * v0 + v1 * v1 + v2 * v2;
    float ri = rsqrtf(d2 + 1e-20f);
    float cu0 = v0 * ri, cu1 = v1 * ri, cu2 = v2 * ri;

    // radial slice from stage
    uint4 s0 = ((const uint4*)stage)[rb];
    uint4 s1 = ((const uint4*)stage)[rb + 1];
    uint4 s2 = ((const uint4*)stage)[rb + 2];

    uint32_t nbi = nb0 + (uint32_t)(i + 1) * (NF * 4);

    // ---- a1: (w1*hsv + w2*(u.ga))*u - (w2/3)*ga   (B-set SGPRs, s2)
    {
      uint32_t d8 = s2.x, d9 = s2.y, d10 = s2.z, d11 = s2.w;
#pragma unroll
      for (int c = 0; c < 4; c++) {
        float w1c = (c == 0) ? LOF(d8) : (c == 1) ? HIF(d8) : (c == 2) ? LOF(d9) : HIF(d9);
        float w2c = (c == 0) ? LOF(d10) : (c == 1) ? HIF(d10) : (c == 2) ? LOF(d11) : HIF(d11);
        float g0 = SF(rB, 4 + c * 3), g1 = SF(rB, 5 + c * 3), g2 = SF(rB, 6 + c * 3);
        float qd = cu0 * g0 + cu1 * g1 + cu2 * g2;
        float coef = w1c * SF(rB, c) + w2c * qd;
        float t3 = w2c * (1.0f / 3.0f);
        a1[c * 3]     += coef * cu0 - t3 * g0;
        a1[c * 3 + 1] += coef * cu1 - t3 * g1;
        a1[c * 3 + 2] += coef * cu2 - t3 * g2;
      }
    }
    // reload B-set + xs for i+1 (hides under a0 compute)
    if (i + 1 < CHUNK) {
      rB = sload16(nf, nbi + 128);
      rX = sload4 (nf, nrow0 + (uint32_t)(i + 1) * (NF * 4) + 1536);
    }

    // ---- a0: w0*hm + w3*(u . p)   (A-set SGPRs, s0/s1)
    {
      uint32_t dw[8];
      *(uint4*)(dw + 0) = s0; *(uint4*)(dw + 4) = s1;
#pragma unroll
      for (int k = 0; k < 8; k++) {
        float w0k = (k & 1) ? HIF(dw[k >> 1]) : LOF(dw[k >> 1]);
        float w3k = (k & 1) ? HIF(dw[4 + (k >> 1)]) : LOF(dw[4 + (k >> 1)]);
        float dv = cu0 * SF(rA0, 8 + k) + cu1 * SF(rA1, k) + cu2 * SF(rA1, 8 + k);
        a0[k] += w0k * SF(rA0, k) + w3k * dv;
      }
    }
    // reload A-set for i+1 (hides under barrier + stage write)
    if (i + 1 < CHUNK) {
      rA0 = sload16(nf, nbi);
      rA1 = sload16(nf, nbi + 64);
    }
  }

  float* pw = partial + (size_t)(b * SSPLIT + ss) * ACC * NN;
#pragma unroll
  for (int k = 0; k < 8; k++) pw[(w * 8 + k) * NN + r] = a0[k];
#pragma unroll
  for (int c = 0; c < 4; c++) {
#pragma unroll
    for (int i = 0; i < 3; i++)
      pw[(64 + (w * 4 + c) * 3 + i) * NN + r] = a1[c * 3 + i];
  }
}

// ---------------------------------------------------------------------------
// Coalesced ss-reduction: agg[b][feat][n] = sum_ss partial[b][ss][feat][n].
// ---------------------------------------------------------------------------
__global__ void reduce_k(const float* __restrict__ partial, float* __restrict__ agg) {
  int idx2 = blockIdx.x * 512 + threadIdx.x;      // over BB*ACC*NN/2 elements
  int b    = idx2 / (ACC * NN / 2);
  int rem  = idx2 - b * (ACC * NN / 2);
  const float2* src = (const float2*)(partial + (size_t)b * SSPLIT * ACC * NN) + rem;
  float2 a = make_float2(0.0f, 0.0f);
#pragma unroll 8
  for (int ss = 0; ss < SSPLIT; ss++) {
    float2 p = src[(size_t)ss * (ACC * NN / 2)];
    a.x += p.x; a.y += p.y;
  }
  ((float2*)(agg + (size_t)b * ACC * NN))[rem] = a;
}

// ---------------------------------------------------------------------------
// Polynomial correction + node update. 4 waves x 2 node-iters per block.
// ---------------------------------------------------------------------------
__global__ void update_k(const float* __restrict__ agg, const float* __restrict__ Wc,
                         const float* __restrict__ Wself,
                         float* __restrict__ h_s, float* __restrict__ h_v) {
  int blk  = blockIdx.x;    // BB*NN/8
  int tid  = threadIdx.x;   // 256
  int wid  = tid >> 6;
  int lane = tid & 63;
  __shared__ float a0s[4][F0], a2s[4][F0], a3s[4][F0], hss[4][F0];
  const float invn = 1.0f / (float)NN;
  for (int it = 0; it < 2; it++) {
    int node = blk * 8 + it * 4 + wid;
    int b = node >> 9, n = node & 511;
    float a = agg[((size_t)b * ACC + lane) * NN + n] * invn;
    a0s[wid][lane] = a; a2s[wid][lane] = a * a; a3s[wid][lane] = a * a * a;
    hss[wid][lane] = h_s[(size_t)node * F0 + lane];
    for (int o = lane; o < 96; o += 64) {
      float v = agg[((size_t)b * ACC + 64 + o) * NN + n];
      h_v[(size_t)node * F1 * 3 + o] += v * invn;
    }
    __syncthreads();
    float val = 0.0f;
    for (int f = 0; f < F0; f++) {
      val += hss[wid][f] * Wself[f * F0 + lane];
      val += a0s[wid][f] * Wc[(0 * F0 + f) * F0 + lane];
      val += a2s[wid][f] * Wc[(1 * F0 + f) * F0 + lane];
      val += a3s[wid][f] * Wc[(2 * F0 + f) * F0 + lane];
    }
    h_s[(size_t)node * F0 + lane] = val;
    __syncthreads();
  }
}

// Output head: vecf = h_v @ Woutv (first), inv = silu(h_s)@Wouts@Wfin + bfin.
// 4 waves x 2 node-iters per block.
__global__ void out_k(const float* __restrict__ h_s, const float* __restrict__ h_v,
                      const float* __restrict__ Wouts, const float* __restrict__ Wfin,
                      const float* __restrict__ bfin, const float* __restrict__ Woutv,
                      float* __restrict__ out) {
  int blk  = blockIdx.x;    // BB*NN/8
  int tid  = threadIdx.x;   // 256
  int wid  = tid >> 6;
  int lane = tid & 63;
  __shared__ float t[4][F0], g[4][NINVD];
  for (int it = 0; it < 2; it++) {
    int node = blk * 8 + it * 4 + wid;
    float h = h_s[(size_t)node * F0 + lane];
    t[wid][lane] = h / (1.0f + __expf(-h));
    __syncthreads();
    float a = 0.0f;
    for (int f = 0; f < F0; f++) a += t[wid][f] * Wouts[f * NINVD + lane];
    g[wid][lane] = a;
    __syncthreads();
    float v = bfin[lane];
    for (int k = 0; k < NINVD; k++) v += g[wid][k] * Wfin[k * NINVD + lane];
    out[INV_OFF + (size_t)node * NINVD + lane] = v;
    if (lane < NVECD * 3) {
      int gg = lane / 3, i = lane - gg * 3;
      float s = 0.0f;
      for (int f = 0; f < F1; f++)
        s += h_v[(size_t)node * F1 * 3 + f * 3 + i] * Woutv[f * NVECD + gg];
      out[(size_t)node * (NVECD * 3) + lane] = s;
    }
    __syncthreads();
  }
}

extern "C" void kernel_launch(void* const* d_in, const int* in_sizes, int n_in,
                              void* d_out, int out_size, void* d_ws, size_t ws_size,
                              hipStream_t stream) {
  const float* x     = (const float*)d_in[0];
  // d_in[1] senders, d_in[2] receivers: dense-graph structure is known, unused.
  const float* embed = (const float*)d_in[3];
  const float* Wr1   = (const float*)d_in[4];
  const float* Wr2   = (const float*)d_in[5];
  const float* Wm    = (const float*)d_in[6];
  const float* Wc    = (const float*)d_in[7];
  const float* Wself = (const float*)d_in[8];
  const float* Wsv   = (const float*)d_in[9];
  const float* Wvv   = (const float*)d_in[10];
  const float* Wv0   = (const float*)d_in[11];
  const float* Wouts = (const float*)d_in[12];
  const float* Woutv = (const float*)d_in[13];
  const float* Wfin  = (const float*)d_in[14];
  const float* bfin  = (const float*)d_in[15];
  float* out = (float*)d_out;

  char* ws = (char*)d_ws;
  size_t off = 0;
  auto wsalloc = [&](size_t bytes) {
    void* p = ws + off;
    off += (bytes + 255) & ~(size_t)255;
    return p;
  };
  __hip_bfloat16* table = (__hip_bfloat16*)wsalloc((size_t)LNUM * (TROWS + 1) * RWN * 2);
  float* h_s     = (float*)wsalloc((size_t)BB * NN * F0 * 4);
  float* h_v     = (float*)wsalloc((size_t)BB * NN * F1 * 3 * 4);
  float* nf      = (float*)wsalloc((size_t)BB * NN * NF * 4);
  float* partial = (float*)wsalloc((size_t)BB * SSPLIT * ACC * NN * 4);
  float* agg     = (float*)wsalloc((size_t)BB * ACC * NN * 4);
  // total workspace: ~48 MB

  table_k<<<LNUM * 130, 192, 0, stream>>>(Wr1, Wr2, table);
  init_k<<<(BB * NN * F1 * 3 + 255) / 256, 256, 0, stream>>>(embed, h_s, h_v);
  for (int l = 0; l < LNUM; l++) {
    nodeprep_k<<<BB * NN / 8, 256, 0, stream>>>(h_s, h_v, x,
                                                Wm + l * F0 * F0, Wsv + l * F0 * F1,
                                                Wvv + l * F1 * F1, Wv0 + l * F1 * F0, nf);
    msg_k<<<BB * RTILES * SSPLIT, 512, 0, stream>>>(nf, table + (size_t)l * (TROWS + 1) * RWN,
                                                    x, partial);
    reduce_k<<<BB * ACC * NN / 2 / 512, 512, 0, stream>>>(partial, agg);
    update_k<<<BB * NN / 8, 256, 0, stream>>>(agg, Wc + l * 3 * F0 * F0,
                                              Wself + l * F0 * F0, h_s, h_v);
  }
  out_k<<<BB * NN / 8, 256, 0, stream>>>(h_s, h_v, Wouts, Wfin, bfin, Woutv, out);
}

// Round 10
// 149.413 us; speedup vs baseline: 1.7927x; 1.7927x over previous
//
#include <hip/hip_runtime.h>
#include <hip/hip_bf16.h>
#include <stdint.h>

// Problem constants
#define LNUM   2
#define F0     64
#define F1     32
#define NBASIS 8
#define WH     64     // radial MLP hidden width
#define RWN    192    // 2*F0 + 2*F1
#define NINVD  64
#define NVECD  16
#define BB     4
#define NN     512

// Tuning constants
#define TROWS  2048        // table rows over d in [0,8); rw(d>6) ~ 0 (no bias)
#define TSCALE 256.0f      // rows per unit d
#define NF     416         // per-node row: 8 slices x 48 [hm8|p0 8|p1 8|p2 8|hsv4|ga12] | xs3 | pad
#define SSPLIT 32          // sender splits
#define CHUNK  16          // NN / SSPLIT senders per block
#define ACC    160         // 64 (a0) + 96 (a1) accumulated features
#define RTILES 8           // receiver tiles of 64 per batch
#define TBLK   16          // table rows per block
#define INV_OFF (BB * NN * NVECD * 3)   // vecf comes first in d_out

typedef float f32x4 __attribute__((ext_vector_type(4)));
typedef uint32_t u32x16 __attribute__((ext_vector_type(16)));
typedef uint32_t u32x4v __attribute__((ext_vector_type(4)));

#define LOF(u) __uint_as_float((u) << 16)
#define HIF(u) __uint_as_float((u) & 0xffff0000u)
#define SF(vec, k) __uint_as_float((uint32_t)(vec)[k])

// Wave-uniform scalar loads (SMEM pipe). Readiness is guaranteed by the
// mandatory lgkmcnt(0) drain at the next __syncthreads (plus explicit
// waitcnt+sched_barrier at the consume site, per guide rule #18).
__device__ __forceinline__ u32x16 sload16(const float* base, uint32_t boff) {
  u32x16 r;
  asm volatile("s_load_dwordx16 %0, %1, %2" : "=s"(r) : "s"(base), "s"(boff));
  return r;
}
__device__ __forceinline__ u32x4v sload4(const float* base, uint32_t boff) {
  u32x4v r;
  asm volatile("s_load_dwordx4 %0, %1, %2" : "=s"(r) : "s"(base), "s"(boff));
  return r;
}

// ---------------------------------------------------------------------------
// Radial table: rw(d) = silu(rb(d) @ Wr1) @ Wr2, stored bf16, columns permuted
// into 8 slices of 24 = [w0(8)|w3(8)|w1(4)|w2(4)]; row stride 384 B.
// Row TROWS is all zeros (masked diagonal).
// TBLK=16 rows per block so Wr2 reads amortize 16x (kept from R9: measured
// correct, grid 260 x 192 keeps full occupancy).
// ---------------------------------------------------------------------------
__global__ void table_k(const float* __restrict__ Wr1, const float* __restrict__ Wr2,
                        __hip_bfloat16* __restrict__ table) {
  int blk = blockIdx.x;                  // 0 .. LNUM*130-1
  int l   = blk / 130;
  int bj  = blk - l * 130;
  int j0  = bj * TBLK;
  int t   = threadIdx.x;                 // 0..191
  __shared__ float hsh[TBLK][WH];
  // phase 1: hidden activations for TBLK rows (rows >= TROWS get h = 0)
  for (int idx = t; idx < TBLK * WH; idx += 192) {
    int rr = idx >> 6, hid = idx & 63;
    int j = j0 + rr;
    float val = 0.0f;
    if (j < TROWS) {
      float d = (float)j * (1.0f / TSCALE);
      float acc = 0.0f;
#pragma unroll
      for (int b = 0; b < NBASIS; b++) {
        float dd = d - (4.0f / 7.0f) * (float)b;   // centers = linspace(0,4,8)
        acc += __expf(-4.0f * dd * dd) * Wr1[(l * NBASIS + b) * WH + hid];
      }
      val = acc / (1.0f + __expf(-acc));           // silu
    }
    hsh[rr][hid] = val;
  }
  __syncthreads();
  // phase 2: one permuted output column per thread, all TBLK rows
  int w = t / 24, o = t - w * 24;
  int col;
  if      (o < 8)  col = 8 * w + o;              // w0 slice (cols 0..63)
  else if (o < 16) col = 64 + 8 * w + (o - 8);   // w3 slice (64..127)
  else if (o < 20) col = 128 + 4 * w + (o - 16); // w1 slice (128..159)
  else             col = 160 + 4 * w + (o - 20); // w2 slice (160..191)
  float acc[TBLK];
#pragma unroll
  for (int rr = 0; rr < TBLK; rr++) acc[rr] = 0.0f;
  for (int k = 0; k < WH; k++) {
    float wgt = Wr2[(l * WH + k) * RWN + col];
#pragma unroll
    for (int rr = 0; rr < TBLK; rr++) acc[rr] += hsh[rr][k] * wgt;
  }
#pragma unroll
  for (int rr = 0; rr < TBLK; rr++) {
    int j = j0 + rr;
    if (j <= TROWS)
      table[(size_t)(l * (TROWS + 1) + j) * RWN + t] = __float2bfloat16(acc[rr]);
  }
}

// h_s = broadcast embed row; h_v = 0
__global__ void init_k(const float* __restrict__ embed,
                       float* __restrict__ h_s, float* __restrict__ h_v) {
  int i = blockIdx.x * 256 + threadIdx.x;
  if (i < BB * NN * F0) h_s[i] = embed[i % F0];
  if (i < BB * NN * F1 * 3) h_v[i] = 0.0f;
}

// ---------------------------------------------------------------------------
// Per-node precompute, slice-major layout (weights pre-offset by caller) —
// EXACT R7 structure: 64-thread blocks, 2048 blocks (8/CU -> TLP hides the
// L2 weight-load latency; R9's 8-nodes/block collapse proved occupancy is
// the binding constraint here, not weight reuse).
// nf[node] = 8 slices of 48 floats: [hm(8)|p0(8)|p1(8)|p2(8)|hsv(4)|ga(12)]
//            then xs at 384..386; row stride 416 floats (1664 B).
// ---------------------------------------------------------------------------
__global__ void nodeprep_k(const float* __restrict__ h_s, const float* __restrict__ h_v,
                           const float* __restrict__ x,
                           const float* __restrict__ Wm, const float* __restrict__ Wsv,
                           const float* __restrict__ Wvv, const float* __restrict__ Wv0,
                           float* __restrict__ nf) {
  int node = blockIdx.x;      // 0 .. BB*NN-1
  int lane = threadIdx.x;     // 64
  __shared__ float hs[F0];
  __shared__ float hv[F1 * 3];
  hs[lane] = h_s[(size_t)node * F0 + lane];
  hv[lane] = h_v[(size_t)node * F1 * 3 + lane];
  if (lane < 32) hv[64 + lane] = h_v[(size_t)node * F1 * 3 + 64 + lane];
  __syncthreads();
  float* out = nf + (size_t)node * NF;
  {  // hm[f] -> slice f>>3, pos f&7
    float a = 0.0f;
    for (int k = 0; k < F0; k++) a += hs[k] * Wm[k * F0 + lane];
    out[(lane >> 3) * 48 + (lane & 7)] = a;
  }
  if (lane < F1) {  // hsv[c] -> slice c>>2, pos 32 + (c&3)
    float a = 0.0f;
    for (int k = 0; k < F0; k++) a += hs[k] * Wsv[k * F1 + lane];
    out[(lane >> 2) * 48 + 32 + (lane & 3)] = a;
  }
  for (int o = lane; o < 96; o += 64) {  // ga: hvv[ch][i] -> slice ch>>2, 36+(ch&3)*3+i
    int ch = o / 3, i = o - ch * 3;
    float a = 0.0f;
    for (int f = 0; f < F1; f++) a += hv[f * 3 + i] * Wvv[f * F1 + ch];
    out[(ch >> 2) * 48 + 36 + (ch & 3) * 3 + i] = a;
  }
  for (int o = lane; o < 192; o += 64) {  // p_i: hv0[i][f] -> slice f>>3, 8+8i+(f&7)
    int i = o >> 6, f = o & 63;
    float a = 0.0f;
    for (int c = 0; c < F1; c++) a += hv[c * 3 + i] * Wv0[c * F0 + f];
    out[(f >> 3) * 48 + 8 + 8 * i + (f & 7)] = a;
  }
  if (lane < 3) out[384 + lane] = x[(size_t)node * 3 + lane];
}

// ---------------------------------------------------------------------------
// Message + scatter — EXACT R7 structure (proven): cooperative radial-row
// staging, single stage buffer, two barriers per sender-iteration; sender
// features via s_load into SGPRs.
// ---------------------------------------------------------------------------
#define LOADNEXT(ii)                                                      \
  {                                                                       \
    int ja0 = jt[ii][e0], ja1 = jt[ii][e1], ja2 = jt[ii][e2];             \
    c0 = *(const uint4*)(tb + (size_t)ja0 * 384 + bo0);                   \
    c1 = *(const uint4*)(tb + (size_t)ja1 * 384 + bo1);                   \
    c2 = *(const uint4*)(tb + (size_t)ja2 * 384 + bo2);                   \
  }

__launch_bounds__(512, 6)
__global__ void msg_k(const float* __restrict__ nf, const __hip_bfloat16* __restrict__ table_l,
                      const float* __restrict__ x, float* __restrict__ partial) {
  __shared__ uint32_t stage[6400];       // 25,600 B = 64 rows x 400 B
  __shared__ uint16_t jt[CHUNK][64];     //  2,048 B
  int bid = blockIdx.x;
  int b   = bid >> 8;                    // /(RTILES*SSPLIT)
  int rem = bid & 255;
  int rt  = rem >> 5;                    // receiver tile
  int ss  = rem & 31;                    // sender chunk
  int tid  = threadIdx.x;
  int w    = tid >> 6;                   // feature slice 0..7
  int lane = tid & 63;                   // local receiver
  int r    = rt * 64 + lane;
  int wu   = __builtin_amdgcn_readfirstlane(w);

  // precompute (sender, receiver) table-row indices for this block
#pragma unroll
  for (int m = 0; m < 2; m++) {
    int idx = tid + 512 * m;             // 1024 = CHUNK*64 entries
    int si = idx >> 6, e = idx & 63;
    int s = ss * CHUNK + si, rr = rt * 64 + e;
    const float* ps = x + ((size_t)b * NN + s) * 3;
    const float* pr = x + ((size_t)b * NN + rr) * 3;
    float v0 = pr[0] - ps[0], v1 = pr[1] - ps[1], v2 = pr[2] - ps[2];
    float d = sqrtf(v0 * v0 + v1 * v1 + v2 * v2);
    int j = (int)fminf(d * TSCALE + 0.5f, (float)(TROWS - 1));
    if (s == rr) j = TROWS;              // diagonal -> zero row
    jt[si][e] = (uint16_t)j;
  }

  const float* xp = x + ((size_t)b * NN + r) * 3;
  float xr0 = xp[0], xr1 = xp[1], xr2 = xp[2];

  // staging chunk map: q = tid + 512k -> row e = q/24, part p = q%24
  int q0 = tid, q1 = tid + 512, q2 = tid + 1024;
  int e0 = q0 / 24, p0 = q0 - 24 * e0;
  int e1 = q1 / 24, p1 = q1 - 24 * e1;
  int e2 = q2 / 24, p2 = q2 - 24 * e2;
  int wi0 = 25 * e0 + p0, wi1 = 25 * e1 + p1, wi2 = 25 * e2 + p2;
  int bo0 = p0 * 16, bo1 = p1 * 16, bo2 = p2 * 16;
  const char* tb = (const char*)table_l;

  float a0[8];
  float a1[12];
#pragma unroll
  for (int k = 0; k < 8; k++) a0[k] = 0.0f;
#pragma unroll
  for (int k = 0; k < 12; k++) a1[k] = 0.0f;

  __syncthreads();                       // jt ready

  uint4 c0, c1, c2;
  LOADNEXT(0);

  // SGPR feature prologue for sender 0
  uint32_t nrow0 = (uint32_t)(b * NN + ss * CHUNK) * (NF * 4);
  uint32_t nb0   = nrow0 + (uint32_t)wu * 192;
  u32x16 rB  = sload16(nf, nb0 + 128);   // hsv|ga
  u32x4v rX  = sload4 (nf, nrow0 + 1536);// xs
  u32x16 rA0 = sload16(nf, nb0);         // hm|p0
  u32x16 rA1 = sload16(nf, nb0 + 64);    // p1|p2

  int rb = 25 * lane + 3 * w;            // this thread's stage slice base

  for (int i = 0; i < CHUNK; i++) {
    __syncthreads();                     // stage free (prev compute done)
    ((uint4*)stage)[wi0] = c0;           // vmcnt auto-wait before ds_write
    ((uint4*)stage)[wi1] = c1;
    ((uint4*)stage)[wi2] = c2;
    __syncthreads();                     // stage ready (drains lgkm: s_loads done)
    if (i + 1 < CHUNK) LOADNEXT(i + 1);  // next rows fetched during compute
    asm volatile("s_waitcnt lgkmcnt(0)" ::: "memory");
    __builtin_amdgcn_sched_barrier(0);

    // geometry (xs in SGPRs)
    float v0 = xr0 - SF(rX, 0), v1 = xr1 - SF(rX, 1), v2 = xr2 - SF(rX, 2);
    float d2 = v0 * v0 + v1 * v1 + v2 * v2;
    float ri = rsqrtf(d2 + 1e-20f);
    float cu0 = v0 * ri, cu1 = v1 * ri, cu2 = v2 * ri;

    // radial slice from stage
    uint4 s0 = ((const uint4*)stage)[rb];
    uint4 s1 = ((const uint4*)stage)[rb + 1];
    uint4 s2 = ((const uint4*)stage)[rb + 2];

    uint32_t nbi = nb0 + (uint32_t)(i + 1) * (NF * 4);

    // ---- a1: (w1*hsv + w2*(u.ga))*u - (w2/3)*ga   (B-set SGPRs, s2)
    {
      uint32_t d8 = s2.x, d9 = s2.y, d10 = s2.z, d11 = s2.w;
#pragma unroll
      for (int c = 0; c < 4; c++) {
        float w1c = (c == 0) ? LOF(d8) : (c == 1) ? HIF(d8) : (c == 2) ? LOF(d9) : HIF(d9);
        float w2c = (c == 0) ? LOF(d10) : (c == 1) ? HIF(d10) : (c == 2) ? LOF(d11) : HIF(d11);
        float g0 = SF(rB, 4 + c * 3), g1 = SF(rB, 5 + c * 3), g2 = SF(rB, 6 + c * 3);
        float qd = cu0 * g0 + cu1 * g1 + cu2 * g2;
        float coef = w1c * SF(rB, c) + w2c * qd;
        float t3 = w2c * (1.0f / 3.0f);
        a1[c * 3]     += coef * cu0 - t3 * g0;
        a1[c * 3 + 1] += coef * cu1 - t3 * g1;
        a1[c * 3 + 2] += coef * cu2 - t3 * g2;
      }
    }
    // reload B-set + xs for i+1 (hides under a0 compute)
    if (i + 1 < CHUNK) {
      rB = sload16(nf, nbi + 128);
      rX = sload4 (nf, nrow0 + (uint32_t)(i + 1) * (NF * 4) + 1536);
    }

    // ---- a0: w0*hm + w3*(u . p)   (A-set SGPRs, s0/s1)
    {
      uint32_t dw[8];
      *(uint4*)(dw + 0) = s0; *(uint4*)(dw + 4) = s1;
#pragma unroll
      for (int k = 0; k < 8; k++) {
        float w0k = (k & 1) ? HIF(dw[k >> 1]) : LOF(dw[k >> 1]);
        float w3k = (k & 1) ? HIF(dw[4 + (k >> 1)]) : LOF(dw[4 + (k >> 1)]);
        float dv = cu0 * SF(rA0, 8 + k) + cu1 * SF(rA1, k) + cu2 * SF(rA1, 8 + k);
        a0[k] += w0k * SF(rA0, k) + w3k * dv;
      }
    }
    // reload A-set for i+1 (hides under barrier + stage write)
    if (i + 1 < CHUNK) {
      rA0 = sload16(nf, nbi);
      rA1 = sload16(nf, nbi + 64);
    }
  }

  float* pw = partial + (size_t)(b * SSPLIT + ss) * ACC * NN;
#pragma unroll
  for (int k = 0; k < 8; k++) pw[(w * 8 + k) * NN + r] = a0[k];
#pragma unroll
  for (int c = 0; c < 4; c++) {
#pragma unroll
    for (int i = 0; i < 3; i++)
      pw[(64 + (w * 4 + c) * 3 + i) * NN + r] = a1[c * 3 + i];
  }
}

// ---------------------------------------------------------------------------
// Coalesced ss-reduction: agg[b][feat][n] = sum_ss partial[b][ss][feat][n].
// ---------------------------------------------------------------------------
__global__ void reduce_k(const float* __restrict__ partial, float* __restrict__ agg) {
  int idx2 = blockIdx.x * 512 + threadIdx.x;      // over BB*ACC*NN/2 elements
  int b    = idx2 / (ACC * NN / 2);
  int rem  = idx2 - b * (ACC * NN / 2);
  const float2* src = (const float2*)(partial + (size_t)b * SSPLIT * ACC * NN) + rem;
  float2 a = make_float2(0.0f, 0.0f);
#pragma unroll 8
  for (int ss = 0; ss < SSPLIT; ss++) {
    float2 p = src[(size_t)ss * (ACC * NN / 2)];
    a.x += p.x; a.y += p.y;
  }
  ((float2*)(agg + (size_t)b * ACC * NN))[rem] = a;
}

// ---------------------------------------------------------------------------
// Polynomial correction + node update, reading the small agg array.
// EXACT R7 structure: 64-thread blocks, 2048 blocks (occupancy > reuse).
// ---------------------------------------------------------------------------
__global__ void update_k(const float* __restrict__ agg, const float* __restrict__ Wc,
                         const float* __restrict__ Wself,
                         float* __restrict__ h_s, float* __restrict__ h_v) {
  int node = blockIdx.x;
  int b = node >> 9, n = node & 511;
  int lane = threadIdx.x;   // 64
  __shared__ float a0s[F0], a2s[F0], a3s[F0], hss[F0];
  const float invn = 1.0f / (float)NN;
  float a = agg[((size_t)b * ACC + lane) * NN + n] * invn;
  a0s[lane] = a; a2s[lane] = a * a; a3s[lane] = a * a * a;
  hss[lane] = h_s[(size_t)node * F0 + lane];
  for (int o = lane; o < 96; o += 64) {
    float v = agg[((size_t)b * ACC + 64 + o) * NN + n];
    h_v[(size_t)node * F1 * 3 + o] += v * invn;
  }
  __syncthreads();
  float val = 0.0f;
  for (int f = 0; f < F0; f++) {
    val += hss[f] * Wself[f * F0 + lane];
    val += a0s[f] * Wc[(0 * F0 + f) * F0 + lane];
    val += a2s[f] * Wc[(1 * F0 + f) * F0 + lane];
    val += a3s[f] * Wc[(2 * F0 + f) * F0 + lane];
  }
  h_s[(size_t)node * F0 + lane] = val;
}

// Output head: vecf = h_v @ Woutv (first), inv = silu(h_s)@Wouts@Wfin + bfin.
// EXACT R7 structure: 64-thread blocks, 2048 blocks.
__global__ void out_k(const float* __restrict__ h_s, const float* __restrict__ h_v,
                      const float* __restrict__ Wouts, const float* __restrict__ Wfin,
                      const float* __restrict__ bfin, const float* __restrict__ Woutv,
                      float* __restrict__ out) {
  int node = blockIdx.x;
  int lane = threadIdx.x;   // 64
  __shared__ float t[F0], g[NINVD];
  float h = h_s[(size_t)node * F0 + lane];
  t[lane] = h / (1.0f + __expf(-h));
  __syncthreads();
  float a = 0.0f;
  for (int f = 0; f < F0; f++) a += t[f] * Wouts[f * NINVD + lane];
  g[lane] = a;
  __syncthreads();
  float v = bfin[lane];
  for (int k = 0; k < NINVD; k++) v += g[k] * Wfin[k * NINVD + lane];
  out[INV_OFF + (size_t)node * NINVD + lane] = v;
  if (lane < NVECD * 3) {
    int gg = lane / 3, i = lane - gg * 3;
    float s = 0.0f;
    for (int f = 0; f < F1; f++) s += h_v[(size_t)node * F1 * 3 + f * 3 + i] * Woutv[f * NVECD + gg];
    out[(size_t)node * (NVECD * 3) + lane] = s;
  }
}

extern "C" void kernel_launch(void* const* d_in, const int* in_sizes, int n_in,
                              void* d_out, int out_size, void* d_ws, size_t ws_size,
                              hipStream_t stream) {
  const float* x     = (const float*)d_in[0];
  // d_in[1] senders, d_in[2] receivers: dense-graph structure is known, unused.
  const float* embed = (const float*)d_in[3];
  const float* Wr1   = (const float*)d_in[4];
  const float* Wr2   = (const float*)d_in[5];
  const float* Wm    = (const float*)d_in[6];
  const float* Wc    = (const float*)d_in[7];
  const float* Wself = (const float*)d_in[8];
  const float* Wsv   = (const float*)d_in[9];
  const float* Wvv   = (const float*)d_in[10];
  const float* Wv0   = (const float*)d_in[11];
  const float* Wouts = (const float*)d_in[12];
  const float* Woutv = (const float*)d_in[13];
  const float* Wfin  = (const float*)d_in[14];
  const float* bfin  = (const float*)d_in[15];
  float* out = (float*)d_out;

  char* ws = (char*)d_ws;
  size_t off = 0;
  auto wsalloc = [&](size_t bytes) {
    void* p = ws + off;
    off += (bytes + 255) & ~(size_t)255;
    return p;
  };
  __hip_bfloat16* table = (__hip_bfloat16*)wsalloc((size_t)LNUM * (TROWS + 1) * RWN * 2);
  float* h_s     = (float*)wsalloc((size_t)BB * NN * F0 * 4);
  float* h_v     = (float*)wsalloc((size_t)BB * NN * F1 * 3 * 4);
  float* nf      = (float*)wsalloc((size_t)BB * NN * NF * 4);
  float* partial = (float*)wsalloc((size_t)BB * SSPLIT * ACC * NN * 4);
  float* agg     = (float*)wsalloc((size_t)BB * ACC * NN * 4);
  // total workspace: ~48 MB

  table_k<<<LNUM * 130, 192, 0, stream>>>(Wr1, Wr2, table);
  init_k<<<(BB * NN * F1 * 3 + 255) / 256, 256, 0, stream>>>(embed, h_s, h_v);
  for (int l = 0; l < LNUM; l++) {
    nodeprep_k<<<BB * NN, 64, 0, stream>>>(h_s, h_v, x,
                                           Wm + l * F0 * F0, Wsv + l * F0 * F1,
                                           Wvv + l * F1 * F1, Wv0 + l * F1 * F0, nf);
    msg_k<<<BB * RTILES * SSPLIT, 512, 0, stream>>>(nf, table + (size_t)l * (TROWS + 1) * RWN,
                                                    x, partial);
    reduce_k<<<BB * ACC * NN / 2 / 512, 512, 0, stream>>>(partial, agg);
    update_k<<<BB * NN, 64, 0, stream>>>(agg, Wc + l * 3 * F0 * F0,
                                         Wself + l * F0 * F0, h_s, h_v);
  }
  out_k<<<BB * NN, 64, 0, stream>>>(h_s, h_v, Wouts, Wfin, bfin, Woutv, out);
}